// Round 5
// baseline (27.488 us; speedup 1.0000x reference)
//
#include <hip/hip_runtime.h>

// Problem constants (match reference)
#define B_TOTAL 16777216
#define NSTEPS 64

#define GRID 2048
#define BLOCK 256
#define ITERS 8  // GRID*BLOCK*ITERS*4 == B_TOTAL exactly

// Native clang vector type: __builtin_nontemporal_store requires a real
// vector type (HIP's float4 is a struct and is rejected).
typedef float vfloat4 __attribute__((ext_vector_type(4)));

// Streaming kernel, latency-hiding order:
//  1. Issue all 8 independent float4 theta loads FIRST (memory pipe busy
//     from cycle ~0).
//  2. While they are in flight, compute surv = prod(1 - sigmoid(raw_gammas))
//     per wave (256 B L2-hot load + __expf + 6-shuffle butterfly) -- its
//     ~1000-cycle dependent chain is hidden under the theta loads.
//  3. Consume loads in order: fused __cosf*surv+oms, NONTEMPORAL store
//     (output has no reuse; keep it out of L2/L3 so thetas stay resident).
__global__ void __launch_bounds__(BLOCK) qm_fused_kernel(
        const float* __restrict__ thetas,
        const float* __restrict__ raw_gammas,
        float* __restrict__ out_expvals,
        float* __restrict__ out_gammas) {
    const int base = blockIdx.x * BLOCK + threadIdx.x;
    const int stride = GRID * BLOCK;

    const vfloat4* __restrict__ t4 = reinterpret_cast<const vfloat4*>(thetas);
    vfloat4* __restrict__ o4 = reinterpret_cast<vfloat4*>(out_expvals);

    // --- 1. issue the big streaming loads first ---
    vfloat4 t[ITERS];
    #pragma unroll
    for (int k = 0; k < ITERS; ++k) {
        t[k] = t4[base + k * stride];
    }

    // --- 2. per-wave surv computation, hidden under the loads ---
    const int lane = threadIdx.x & 63;
    float rg = raw_gammas[lane];
    float g = 1.0f / (1.0f + __expf(-rg));
    if (blockIdx.x == 0 && threadIdx.x < 64) {
        out_gammas[threadIdx.x] = g;
    }
    float v = 1.0f - g;
    #pragma unroll
    for (int off = 32; off > 0; off >>= 1) {
        v *= __shfl_xor(v, off, 64);
    }
    const float surv = v;
    const float oms = 1.0f - surv;

    // --- 3. consume in load order, nontemporal stores ---
    #pragma unroll
    for (int k = 0; k < ITERS; ++k) {
        vfloat4 r;
        r.x = fmaf(__cosf(t[k].x), surv, oms);
        r.y = fmaf(__cosf(t[k].y), surv, oms);
        r.z = fmaf(__cosf(t[k].z), surv, oms);
        r.w = fmaf(__cosf(t[k].w), surv, oms);
        __builtin_nontemporal_store(r, &o4[base + k * stride]);
    }
}

extern "C" void kernel_launch(void* const* d_in, const int* in_sizes, int n_in,
                              void* d_out, int out_size, void* d_ws, size_t ws_size,
                              hipStream_t stream) {
    const float* thetas = (const float*)d_in[0];
    // d_in[1] = phis: unused (RZ does not change <Z>)
    const float* raw_gammas = (const float*)d_in[2];

    float* out_expvals = (float*)d_out;              // [B_TOTAL]
    float* out_gammas = (float*)d_out + B_TOTAL;     // [NSTEPS]

    qm_fused_kernel<<<GRID, BLOCK, 0, stream>>>(thetas, raw_gammas,
                                                out_expvals, out_gammas);
}

// Round 6
// 25.888 us; speedup vs baseline: 1.0618x; 1.0618x over previous
//
#include <hip/hip_runtime.h>

// Problem constants (match reference)
#define B_TOTAL 16777216
#define NSTEPS 64

#define GRID 4096
#define BLOCK 256
#define ITERS 4  // GRID*BLOCK*ITERS*4 == B_TOTAL exactly

// Native clang vector type: __builtin_nontemporal_store requires a real
// vector type (HIP's float4 is a struct and is rejected).
typedef float vfloat4 __attribute__((ext_vector_type(4)));

// Streaming kernel. vs R5: GRID 2048->4096, ITERS 8->4 (same total work).
// 2 scheduling rounds instead of 1 -> dynamic load balance across CUs/XCDs,
// smaller tail. Per-thread: 4 independent float4 loads in flight (64 B/lane),
// still >> latency-BW product needed per CU at 32 waves.
__global__ void __launch_bounds__(BLOCK) qm_fused_kernel(
        const float* __restrict__ thetas,
        const float* __restrict__ raw_gammas,
        float* __restrict__ out_expvals,
        float* __restrict__ out_gammas) {
    const int base = blockIdx.x * BLOCK + threadIdx.x;
    const int stride = GRID * BLOCK;

    const vfloat4* __restrict__ t4 = reinterpret_cast<const vfloat4*>(thetas);
    vfloat4* __restrict__ o4 = reinterpret_cast<vfloat4*>(out_expvals);

    // --- 1. issue the streaming loads first ---
    vfloat4 t[ITERS];
    #pragma unroll
    for (int k = 0; k < ITERS; ++k) {
        t[k] = t4[base + k * stride];
    }

    // --- 2. per-wave surv computation, hidden under the loads ---
    const int lane = threadIdx.x & 63;
    float rg = raw_gammas[lane];
    float g = 1.0f / (1.0f + __expf(-rg));
    if (blockIdx.x == 0 && threadIdx.x < 64) {
        out_gammas[threadIdx.x] = g;
    }
    float v = 1.0f - g;
    #pragma unroll
    for (int off = 32; off > 0; off >>= 1) {
        v *= __shfl_xor(v, off, 64);
    }
    const float surv = v;
    const float oms = 1.0f - surv;

    // --- 3. consume in load order, nontemporal stores ---
    #pragma unroll
    for (int k = 0; k < ITERS; ++k) {
        vfloat4 r;
        r.x = fmaf(__cosf(t[k].x), surv, oms);
        r.y = fmaf(__cosf(t[k].y), surv, oms);
        r.z = fmaf(__cosf(t[k].z), surv, oms);
        r.w = fmaf(__cosf(t[k].w), surv, oms);
        __builtin_nontemporal_store(r, &o4[base + k * stride]);
    }
}

extern "C" void kernel_launch(void* const* d_in, const int* in_sizes, int n_in,
                              void* d_out, int out_size, void* d_ws, size_t ws_size,
                              hipStream_t stream) {
    const float* thetas = (const float*)d_in[0];
    // d_in[1] = phis: unused (RZ does not change <Z>)
    const float* raw_gammas = (const float*)d_in[2];

    float* out_expvals = (float*)d_out;              // [B_TOTAL]
    float* out_gammas = (float*)d_out + B_TOTAL;     // [NSTEPS]

    qm_fused_kernel<<<GRID, BLOCK, 0, stream>>>(thetas, raw_gammas,
                                                out_expvals, out_gammas);
}

// Round 7
// 25.030 us; speedup vs baseline: 1.0982x; 1.0343x over previous
//
#include <hip/hip_runtime.h>

// Problem constants (match reference)
#define B_TOTAL 16777216
#define NSTEPS 64

#define GRID 8192
#define BLOCK 256
#define ITERS 2  // GRID*BLOCK*ITERS*4 == B_TOTAL exactly

// Native clang vector type: __builtin_nontemporal_store requires a real
// vector type (HIP's float4 is a struct and is rejected).
typedef float vfloat4 __attribute__((ext_vector_type(4)));

// Streaming kernel. vs R6: GRID 4096->8192, ITERS 4->2 (same total work).
// 4 scheduling rounds -> finer dynamic load balance across CUs/XCDs,
// smaller straggler tail. 2 independent float4 loads in flight per thread
// (32 B/lane; x32 waves/CU = 32 KB/CU in flight, above latency-BW product).
__global__ void __launch_bounds__(BLOCK) qm_fused_kernel(
        const float* __restrict__ thetas,
        const float* __restrict__ raw_gammas,
        float* __restrict__ out_expvals,
        float* __restrict__ out_gammas) {
    const int base = blockIdx.x * BLOCK + threadIdx.x;
    const int stride = GRID * BLOCK;

    const vfloat4* __restrict__ t4 = reinterpret_cast<const vfloat4*>(thetas);
    vfloat4* __restrict__ o4 = reinterpret_cast<vfloat4*>(out_expvals);

    // --- 1. issue the streaming loads first ---
    vfloat4 t[ITERS];
    #pragma unroll
    for (int k = 0; k < ITERS; ++k) {
        t[k] = t4[base + k * stride];
    }

    // --- 2. per-wave surv computation, hidden under the loads ---
    const int lane = threadIdx.x & 63;
    float rg = raw_gammas[lane];
    float g = 1.0f / (1.0f + __expf(-rg));
    if (blockIdx.x == 0 && threadIdx.x < 64) {
        out_gammas[threadIdx.x] = g;
    }
    float v = 1.0f - g;
    #pragma unroll
    for (int off = 32; off > 0; off >>= 1) {
        v *= __shfl_xor(v, off, 64);
    }
    const float surv = v;
    const float oms = 1.0f - surv;

    // --- 3. consume in load order, nontemporal stores ---
    #pragma unroll
    for (int k = 0; k < ITERS; ++k) {
        vfloat4 r;
        r.x = fmaf(__cosf(t[k].x), surv, oms);
        r.y = fmaf(__cosf(t[k].y), surv, oms);
        r.z = fmaf(__cosf(t[k].z), surv, oms);
        r.w = fmaf(__cosf(t[k].w), surv, oms);
        __builtin_nontemporal_store(r, &o4[base + k * stride]);
    }
}

extern "C" void kernel_launch(void* const* d_in, const int* in_sizes, int n_in,
                              void* d_out, int out_size, void* d_ws, size_t ws_size,
                              hipStream_t stream) {
    const float* thetas = (const float*)d_in[0];
    // d_in[1] = phis: unused (RZ does not change <Z>)
    const float* raw_gammas = (const float*)d_in[2];

    float* out_expvals = (float*)d_out;              // [B_TOTAL]
    float* out_gammas = (float*)d_out + B_TOTAL;     // [NSTEPS]

    qm_fused_kernel<<<GRID, BLOCK, 0, stream>>>(thetas, raw_gammas,
                                                out_expvals, out_gammas);
}

// Round 8
// 24.782 us; speedup vs baseline: 1.1092x; 1.0100x over previous
//
#include <hip/hip_runtime.h>

// Problem constants (match reference)
#define B_TOTAL 16777216
#define NSTEPS 64

#define GRID 16384
#define BLOCK 256
#define ITERS 1  // GRID*BLOCK*ITERS*4 == B_TOTAL exactly

// Native clang vector type: __builtin_nontemporal_store requires a real
// vector type (HIP's float4 is a struct and is rejected).
typedef float vfloat4 __attribute__((ext_vector_type(4)));

// Streaming kernel. vs R7: GRID 8192->16384, ITERS 2->1 (same total work).
// 8 scheduling rounds -> finest-grain dynamic load balance; straggler tail
// ~= 1 float4 per lane. The per-wave surv chain (L2-hot load + __expf +
// 6-shuffle butterfly) hides under the single theta load's ~500-900 cy
// latency.
__global__ void __launch_bounds__(BLOCK) qm_fused_kernel(
        const float* __restrict__ thetas,
        const float* __restrict__ raw_gammas,
        float* __restrict__ out_expvals,
        float* __restrict__ out_gammas) {
    const int idx = blockIdx.x * BLOCK + threadIdx.x;

    const vfloat4* __restrict__ t4 = reinterpret_cast<const vfloat4*>(thetas);
    vfloat4* __restrict__ o4 = reinterpret_cast<vfloat4*>(out_expvals);

    // --- 1. issue the streaming load first ---
    vfloat4 t = t4[idx];

    // --- 2. per-wave surv computation, hidden under the load ---
    const int lane = threadIdx.x & 63;
    float rg = raw_gammas[lane];
    float g = 1.0f / (1.0f + __expf(-rg));
    if (blockIdx.x == 0 && threadIdx.x < 64) {
        out_gammas[threadIdx.x] = g;
    }
    float v = 1.0f - g;
    #pragma unroll
    for (int off = 32; off > 0; off >>= 1) {
        v *= __shfl_xor(v, off, 64);
    }
    const float surv = v;
    const float oms = 1.0f - surv;

    // --- 3. consume, nontemporal store ---
    vfloat4 r;
    r.x = fmaf(__cosf(t.x), surv, oms);
    r.y = fmaf(__cosf(t.y), surv, oms);
    r.z = fmaf(__cosf(t.z), surv, oms);
    r.w = fmaf(__cosf(t.w), surv, oms);
    __builtin_nontemporal_store(r, &o4[idx]);
}

extern "C" void kernel_launch(void* const* d_in, const int* in_sizes, int n_in,
                              void* d_out, int out_size, void* d_ws, size_t ws_size,
                              hipStream_t stream) {
    const float* thetas = (const float*)d_in[0];
    // d_in[1] = phis: unused (RZ does not change <Z>)
    const float* raw_gammas = (const float*)d_in[2];

    float* out_expvals = (float*)d_out;              // [B_TOTAL]
    float* out_gammas = (float*)d_out + B_TOTAL;     // [NSTEPS]

    qm_fused_kernel<<<GRID, BLOCK, 0, stream>>>(thetas, raw_gammas,
                                                out_expvals, out_gammas);
}